// Round 2
// baseline (311.728 us; speedup 1.0000x reference)
//
#include <hip/hip_runtime.h>
#include <math.h>

// Problem constants (B,H,W,C = 16,32,32,512; 32 groups)
#define BATCH 16
#define NTOK  1024
#define CH    512
#define NGRP  32
#define GSZ   16
#define EPSV  1e-3f
#define MTOT  (BATCH*NTOK)          // 16384
#define SCALE 0.04419417382415922f  // 512^-0.5

typedef unsigned short u16;
typedef __attribute__((ext_vector_type(4))) float f32x4;
typedef __attribute__((ext_vector_type(8))) short s16x8;

__device__ __forceinline__ u16 f2bf(float f) {           // RNE float->bf16
    union { float f; unsigned u; } x{f};
    unsigned r = x.u + 0x7fff + ((x.u >> 16) & 1);
    return (u16)(r >> 16);
}
__device__ __forceinline__ u16 cvt_elem(float f)  { return f2bf(f); }
__device__ __forceinline__ u16 cvt_elem(u16 h)    { return h; }

__device__ __forceinline__ void gld16(const u16* g, u16* l) {
    __builtin_amdgcn_global_load_lds(
        (const __attribute__((address_space(1))) void*)g,
        (__attribute__((address_space(3))) void*)l, 16, 0, 0);
}

// ---------------------------------------------------------------- group-norm stats
__global__ __launch_bounds__(256) void gn_stats(const float* __restrict__ x,
                                                float2* __restrict__ stats) {
    int bg = blockIdx.x;             // batch*32 + group
    int b = bg >> 5, g = bg & 31;
    const float* base = x + (size_t)b * NTOK * CH + g * GSZ;
    float s = 0.f, ss = 0.f;
    for (int i = threadIdx.x; i < 4096; i += 256) {
        int p = i >> 2, c4 = i & 3;
        float4 v = *(const float4*)(base + (size_t)p * CH + c4 * 4);
        s  += v.x + v.y + v.z + v.w;
        ss += v.x * v.x + v.y * v.y + v.z * v.z + v.w * v.w;
    }
    for (int off = 32; off; off >>= 1) {
        s  += __shfl_down(s, off);
        ss += __shfl_down(ss, off);
    }
    __shared__ float2 part[4];
    if ((threadIdx.x & 63) == 0) part[threadIdx.x >> 6] = make_float2(s, ss);
    __syncthreads();
    if (threadIdx.x == 0) {
        float S = 0.f, SS = 0.f;
        for (int i = 0; i < 4; i++) { S += part[i].x; SS += part[i].y; }
        float mean = S * (1.f / 16384.f);
        float var  = SS * (1.f / 16384.f) - mean * mean;
        stats[bg] = make_float2(mean, rsqrtf(var + EPSV));
    }
}

// ---------------------------------------------------------------- apply norm -> xn(f32) + xnb(bf16)
__global__ __launch_bounds__(256) void gn_apply(const float* __restrict__ x,
                                                const float2* __restrict__ stats,
                                                const float* __restrict__ gamma,
                                                const float* __restrict__ beta,
                                                float* __restrict__ xn,
                                                u16* __restrict__ xnb) {
    size_t total = (size_t)MTOT * CH / 4;
    for (size_t i4 = (size_t)blockIdx.x * 256 + threadIdx.x; i4 < total;
         i4 += (size_t)gridDim.x * 256) {
        size_t flat = i4 * 4;
        int c = (int)(flat & (CH - 1));
        int b = (int)(flat >> 19);        // /(1024*512)
        int g = c >> 4;
        float2 st = stats[(b << 5) + g];
        float4 xv = *(const float4*)(x + flat);
        float4 gv = *(const float4*)(gamma + c);
        float4 bv = *(const float4*)(beta + c);
        float4 o;
        o.x = (xv.x - st.x) * st.y * gv.x + bv.x;
        o.y = (xv.y - st.x) * st.y * gv.y + bv.y;
        o.z = (xv.z - st.x) * st.y * gv.z + bv.z;
        o.w = (xv.w - st.x) * st.y * gv.w + bv.w;
        *(float4*)(xn + flat) = o;
        uint2 h;
        h.x = (unsigned)f2bf(o.x) | ((unsigned)f2bf(o.y) << 16);
        h.y = (unsigned)f2bf(o.z) | ((unsigned)f2bf(o.w) << 16);
        *(uint2*)(xnb + flat) = h;
    }
}

// ---------------------------------------------------------------- transpose + convert to bf16
// in: [R][C] row-major (TIN = float or u16/bf16) -> out: [C][R] bf16
template <typename TIN>
__global__ __launch_bounds__(256) void transpose_bf16(const TIN* __restrict__ in,
                                                      u16* __restrict__ out,
                                                      int R, int C, long sIn, long sOut) {
    __shared__ u16 tile[64][66];
    int z = blockIdx.z;
    in  += (size_t)z * sIn;
    out += (size_t)z * sOut;
    int r0 = blockIdx.y * 64, c0 = blockIdx.x * 64;
    int t = threadIdx.x;
    for (int i = 0; i < 16; i++) {
        int idx = i * 256 + t;
        int r = idx >> 6, c = idx & 63;
        tile[r][c] = cvt_elem(in[(size_t)(r0 + r) * C + c0 + c]);
    }
    __syncthreads();
    for (int i = 0; i < 16; i++) {
        int idx = i * 256 + t;
        int oc = idx >> 6, orr = idx & 63;      // out row = input col
        out[(size_t)(c0 + oc) * R + r0 + orr] = tile[orr][oc];
    }
}

// ---------------------------------------------------------------- bf16 MFMA GEMM  (C = alpha*A*B^T (+bias) (+res))
// A: [M][K] bf16 row-major; B: [N][K] bf16 row-major (i.e. B^T form).
// 128x128 tile, 256 thr = 4 waves (2x2), each wave 64x64 via 4x4 frags of 16x16x32.
// LDS tiles [128][32] bf16, XOR-swizzled: physical c16 = logical c16 ^ ((row>>1)&3),
// applied on BOTH the global_load_lds source address and the ds_read offset.
template <bool BIAS, bool RES, bool OUTF32>
__global__ __launch_bounds__(256) void gemm_bt(
    const u16* __restrict__ A, const u16* __restrict__ B, void* __restrict__ Cout,
    const float* __restrict__ bias, const float* __restrict__ res,
    int K, int lda, int ldb, int ldc,
    long sA, long sB, long sC, float alpha) {
    __shared__ __align__(16) u16 Asm[4096];   // 8 KB
    __shared__ __align__(16) u16 Bsm[4096];
    int z = blockIdx.z;
    A += (size_t)z * sA;
    B += (size_t)z * sB;
    size_t zc = (size_t)z * sC;

    int t = threadIdx.x;
    int wave = t >> 6, lane = t & 63;
    int wm = wave >> 1, wn = wave & 1;
    int rowA0 = blockIdx.y * 128;
    int colB0 = blockIdx.x * 128;

    // staging: seg s = wave*2+j covers LDS [s*1024 .. +1024) bytes = rows s*16..s*16+15
    int c16log = (lane & 3) ^ ((lane >> 3) & 3);     // pre-swizzled global source
    const u16* aG[2]; const u16* bG[2]; u16* aL[2]; u16* bL[2];
#pragma unroll
    for (int j = 0; j < 2; j++) {
        int s = wave * 2 + j;
        int row = s * 16 + (lane >> 2);
        aL[j] = Asm + s * 512;                       // wave-uniform LDS base
        bL[j] = Bsm + s * 512;
        aG[j] = A + (size_t)(rowA0 + row) * lda + c16log * 8;
        bG[j] = B + (size_t)(colB0 + row) * ldb + c16log * 8;
    }

    // frag-read offsets (ushort units), swizzled
    int kg = lane >> 4;
    int aoff[4], boff[4];
#pragma unroll
    for (int i = 0; i < 4; i++) {
        int ra = wm * 64 + i * 16 + (lane & 15);
        aoff[i] = ra * 32 + (kg ^ ((ra >> 1) & 3)) * 8;
        int rb = wn * 64 + i * 16 + (lane & 15);
        boff[i] = rb * 32 + (kg ^ ((rb >> 1) & 3)) * 8;
    }

    f32x4 acc[4][4] = {};
    for (int kt = 0; kt < K; kt += 32) {
        gld16(aG[0] + kt, aL[0]);
        gld16(aG[1] + kt, aL[1]);
        gld16(bG[0] + kt, bL[0]);
        gld16(bG[1] + kt, bL[1]);
        __syncthreads();                  // drains vmcnt -> tile ready
        s16x8 af[4], bfr[4];
#pragma unroll
        for (int i = 0; i < 4; i++) {
            af[i]  = *(const s16x8*)(Asm + aoff[i]);
            bfr[i] = *(const s16x8*)(Bsm + boff[i]);
        }
#pragma unroll
        for (int mi = 0; mi < 4; mi++)
#pragma unroll
            for (int nj = 0; nj < 4; nj++)
                acc[mi][nj] = __builtin_amdgcn_mfma_f32_16x16x32_bf16(
                    af[mi], bfr[nj], acc[mi][nj], 0, 0, 0);
        __syncthreads();                  // reads done before next overwrite
    }

    // epilogue: D row=(lane>>4)*4+reg, col=lane&15
    int r0 = rowA0 + wm * 64 + (lane >> 4) * 4;
    int c0c = colB0 + wn * 64 + (lane & 15);
#pragma unroll
    for (int mi = 0; mi < 4; mi++) {
#pragma unroll
        for (int nj = 0; nj < 4; nj++) {
            int c = c0c + nj * 16;
            float bv = BIAS ? bias[c] : 0.f;
            f32x4 v = acc[mi][nj];
#pragma unroll
            for (int j = 0; j < 4; j++) {
                int rr = r0 + mi * 16 + j;
                float val = v[j] * alpha + bv;
                if (RES) val += res[(size_t)rr * ldc + c];
                if (OUTF32) ((float*)Cout)[zc + (size_t)rr * ldc + c] = val;
                else        ((u16*)Cout)[zc + (size_t)rr * ldc + c] = f2bf(val);
            }
        }
    }
}

// ---------------------------------------------------------------- row softmax (1024 cols) -> bf16 P
__global__ __launch_bounds__(256) void softmax_rows(const float* __restrict__ s,
                                                    u16* __restrict__ P) {
    size_t row = blockIdx.x;
    const float* p = s + row * 1024;
    int t = threadIdx.x;
    float4 v = *(const float4*)(p + t * 4);
    float m = fmaxf(fmaxf(v.x, v.y), fmaxf(v.z, v.w));
    for (int off = 32; off; off >>= 1) m = fmaxf(m, __shfl_xor(m, off));
    __shared__ float redm[4], reds[4];
    if ((t & 63) == 0) redm[t >> 6] = m;
    __syncthreads();
    m = fmaxf(fmaxf(redm[0], redm[1]), fmaxf(redm[2], redm[3]));
    v.x = __expf(v.x - m); v.y = __expf(v.y - m);
    v.z = __expf(v.z - m); v.w = __expf(v.w - m);
    float sum = v.x + v.y + v.z + v.w;
    for (int off = 32; off; off >>= 1) sum += __shfl_xor(sum, off);
    if ((t & 63) == 0) reds[t >> 6] = sum;
    __syncthreads();
    float inv = 1.f / (reds[0] + reds[1] + reds[2] + reds[3]);
    uint2 h;
    h.x = (unsigned)f2bf(v.x * inv) | ((unsigned)f2bf(v.y * inv) << 16);
    h.y = (unsigned)f2bf(v.z * inv) | ((unsigned)f2bf(v.w * inv) << 16);
    *(uint2*)(P + row * 1024 + t * 4) = h;
}

// ---------------------------------------------------------------- launch
extern "C" void kernel_launch(void* const* d_in, const int* in_sizes, int n_in,
                              void* d_out, int out_size, void* d_ws, size_t ws_size,
                              hipStream_t stream) {
    const float* x     = (const float*)d_in[0];
    const float* gamma = (const float*)d_in[1];
    const float* beta  = (const float*)d_in[2];
    const float* Wq    = (const float*)d_in[3];
    const float* bq    = (const float*)d_in[4];
    const float* Wk    = (const float*)d_in[5];
    const float* bk    = (const float*)d_in[6];
    const float* Wv    = (const float*)d_in[7];
    const float* bv    = (const float*)d_in[8];
    const float* Wp    = (const float*)d_in[9];
    const float* bp    = (const float*)d_in[10];
    float* out = (float*)d_out;

    const size_t SZ  = (size_t)MTOT * CH;        // 8,388,608
    const size_t NSZ = (size_t)NTOK * CH;        // 524,288 (per-batch act)
    const size_t SCB = (size_t)NTOK * NTOK;      // 1,048,576 (per-batch scores)

    // ---- workspace carve (bytes) ----
    char* p = (char*)d_ws;
    float*  xn    = (float*)p;           p += SZ * 4;                  // 33.5 MB
    float2* stats = (float2*)p;          p += 512 * sizeof(float2);
    p = (char*)(((size_t)p + 255) & ~(size_t)255);
    u16* WTq = (u16*)p;                  p += CH * CH * 2;             // 0.5 MB each
    u16* WTk = (u16*)p;                  p += CH * CH * 2;
    u16* WTv = (u16*)p;                  p += CH * CH * 2;
    u16* WTp = (u16*)p;                  p += CH * CH * 2;
    u16* xnb = (u16*)p;                  p += SZ * 2;                  // 16.8 MB each
    u16* qb  = (u16*)p;                  p += SZ * 2;
    u16* kb  = (u16*)p;                  p += SZ * 2;
    u16* vb  = (u16*)p;                  p += SZ * 2;
    u16* vt  = (u16*)p;                  p += SZ * 2;
    u16* ao  = (u16*)p;                  p += SZ * 2;
    u16* P   = (u16*)p;                  p += (size_t)BATCH * SCB * 2; // 33.5 MB
    float* sc = (float*)p;
    size_t used = (size_t)(p - (char*)d_ws);
    bool full = ws_size >= used + (size_t)BATCH * SCB * 4;             // +67 MB scores

    dim3 blk(256);

    gn_stats<<<BATCH * NGRP, blk, 0, stream>>>(x, stats);
    gn_apply<<<2048, blk, 0, stream>>>(x, stats, gamma, beta, xn, xnb);

    // weights -> bf16 transposed [N][K]
    transpose_bf16<float><<<dim3(8, 8, 1), blk, 0, stream>>>(Wq, WTq, CH, CH, 0, 0);
    transpose_bf16<float><<<dim3(8, 8, 1), blk, 0, stream>>>(Wk, WTk, CH, CH, 0, 0);
    transpose_bf16<float><<<dim3(8, 8, 1), blk, 0, stream>>>(Wv, WTv, CH, CH, 0, 0);
    transpose_bf16<float><<<dim3(8, 8, 1), blk, 0, stream>>>(Wp, WTp, CH, CH, 0, 0);

    // QKV projections: [16384x512] = xnb @ WT^T (+bias) -> bf16
    gemm_bt<true, false, false><<<dim3(4, 128, 1), blk, 0, stream>>>(
        xnb, WTq, qb, bq, nullptr, CH, CH, CH, CH, 0, 0, 0, 1.f);
    gemm_bt<true, false, false><<<dim3(4, 128, 1), blk, 0, stream>>>(
        xnb, WTk, kb, bk, nullptr, CH, CH, CH, CH, 0, 0, 0, 1.f);
    gemm_bt<true, false, false><<<dim3(4, 128, 1), blk, 0, stream>>>(
        xnb, WTv, vb, bv, nullptr, CH, CH, CH, CH, 0, 0, 0, 1.f);

    // V -> V^T per batch: [1024][512] -> [512][1024]
    transpose_bf16<u16><<<dim3(8, 16, BATCH), blk, 0, stream>>>(
        vb, vt, NTOK, CH, (long)NSZ, (long)NSZ);

    if (full) {
        // scores = q @ k^T * scale (batched), fp32
        gemm_bt<false, false, true><<<dim3(8, 8, BATCH), blk, 0, stream>>>(
            qb, kb, sc, nullptr, nullptr, CH, CH, CH, NTOK,
            (long)NSZ, (long)NSZ, (long)SCB, SCALE);
        softmax_rows<<<BATCH * NTOK, blk, 0, stream>>>(sc, P);
    } else {
        for (int b = 0; b < BATCH; b++) {
            gemm_bt<false, false, true><<<dim3(8, 8, 1), blk, 0, stream>>>(
                qb + b * NSZ, kb + b * NSZ, sc, nullptr, nullptr,
                CH, CH, CH, NTOK, 0, 0, 0, SCALE);
            softmax_rows<<<NTOK, blk, 0, stream>>>(sc, P + b * SCB);
        }
    }

    // out_attn = P @ V (batched): A=P[1024][1024], BT=vt[512][1024] -> ao bf16
    gemm_bt<false, false, false><<<dim3(4, 8, BATCH), blk, 0, stream>>>(
        P, vt, ao, nullptr, nullptr, NTOK, NTOK, NTOK, CH,
        (long)SCB, (long)NSZ, (long)NSZ, 1.f);

    // proj + bias + residual(xn f32) -> out f32
    gemm_bt<true, true, true><<<dim3(4, 128, 1), blk, 0, stream>>>(
        ao, WTp, out, bp, xn, CH, CH, CH, CH, 0, 0, 0, 1.f);
}

// Round 3
// 270.007 us; speedup vs baseline: 1.1545x; 1.1545x over previous
//
#include <hip/hip_runtime.h>
#include <math.h>

// Problem constants (B,H,W,C = 16,32,32,512; 32 groups)
#define BATCH 16
#define NTOK  1024
#define CH    512
#define NGRP  32
#define GSZ   16
#define EPSV  1e-3f
#define MTOT  (BATCH*NTOK)          // 16384
#define SCALE 0.04419417382415922f  // 512^-0.5
#define SEXP  (SCALE*1.4426950408889634f)   // scale*log2(e), for exp2

typedef unsigned short u16;
typedef __attribute__((ext_vector_type(4))) float f32x4;
typedef __attribute__((ext_vector_type(8))) short s16x8;

__device__ __forceinline__ u16 f2bf(float f) {           // RNE float->bf16
    union { float f; unsigned u; } x{f};
    unsigned r = x.u + 0x7fff + ((x.u >> 16) & 1);
    return (u16)(r >> 16);
}

__device__ __forceinline__ void gld16(const u16* g, u16* l) {
    __builtin_amdgcn_global_load_lds(
        (const __attribute__((address_space(1))) void*)g,
        (__attribute__((address_space(3))) void*)l, 16, 0, 0);
}

// ---------------------------------------------------------------- group-norm stats
__global__ __launch_bounds__(256) void gn_stats(const float* __restrict__ x,
                                                float2* __restrict__ stats) {
    int bg = blockIdx.x;             // batch*32 + group
    int b = bg >> 5, g = bg & 31;
    const float* base = x + (size_t)b * NTOK * CH + g * GSZ;
    float s = 0.f, ss = 0.f;
    for (int i = threadIdx.x; i < 4096; i += 256) {
        int p = i >> 2, c4 = i & 3;
        float4 v = *(const float4*)(base + (size_t)p * CH + c4 * 4);
        s  += v.x + v.y + v.z + v.w;
        ss += v.x * v.x + v.y * v.y + v.z * v.z + v.w * v.w;
    }
    for (int off = 32; off; off >>= 1) {
        s  += __shfl_down(s, off);
        ss += __shfl_down(ss, off);
    }
    __shared__ float2 part[4];
    if ((threadIdx.x & 63) == 0) part[threadIdx.x >> 6] = make_float2(s, ss);
    __syncthreads();
    if (threadIdx.x == 0) {
        float S = 0.f, SS = 0.f;
        for (int i = 0; i < 4; i++) { S += part[i].x; SS += part[i].y; }
        float mean = S * (1.f / 16384.f);
        float var  = SS * (1.f / 16384.f) - mean * mean;
        stats[bg] = make_float2(mean, rsqrtf(var + EPSV));
    }
}

// ---------------------------------------------------------------- apply norm -> xn(f32) + xnb(bf16)
__global__ __launch_bounds__(256) void gn_apply(const float* __restrict__ x,
                                                const float2* __restrict__ stats,
                                                const float* __restrict__ gamma,
                                                const float* __restrict__ beta,
                                                float* __restrict__ xn,
                                                u16* __restrict__ xnb) {
    size_t total = (size_t)MTOT * CH / 4;
    for (size_t i4 = (size_t)blockIdx.x * 256 + threadIdx.x; i4 < total;
         i4 += (size_t)gridDim.x * 256) {
        size_t flat = i4 * 4;
        int c = (int)(flat & (CH - 1));
        int b = (int)(flat >> 19);
        int g = c >> 4;
        float2 st = stats[(b << 5) + g];
        float4 xv = *(const float4*)(x + flat);
        float4 gv = *(const float4*)(gamma + c);
        float4 bv = *(const float4*)(beta + c);
        float4 o;
        o.x = (xv.x - st.x) * st.y * gv.x + bv.x;
        o.y = (xv.y - st.x) * st.y * gv.y + bv.y;
        o.z = (xv.z - st.x) * st.y * gv.z + bv.z;
        o.w = (xv.w - st.x) * st.y * gv.w + bv.w;
        *(float4*)(xn + flat) = o;
        uint2 h;
        h.x = (unsigned)f2bf(o.x) | ((unsigned)f2bf(o.y) << 16);
        h.y = (unsigned)f2bf(o.z) | ((unsigned)f2bf(o.w) << 16);
        *(uint2*)(xnb + flat) = h;
    }
}

// ---------------------------------------------------------------- weights: transpose f32->bf16, all 4 in one dispatch
__global__ __launch_bounds__(256) void weights_prep(
    const float* __restrict__ Wq, const float* __restrict__ Wk,
    const float* __restrict__ Wv, const float* __restrict__ Wp,
    u16* __restrict__ WTqkv, u16* __restrict__ WTp) {
    int z = blockIdx.z;
    const float* src = z == 0 ? Wq : z == 1 ? Wk : z == 2 ? Wv : Wp;
    u16* dst = z < 3 ? WTqkv + (size_t)z * CH * CH : WTp;
    __shared__ u16 tile[64][66];
    int r0 = blockIdx.y * 64, c0 = blockIdx.x * 64;
    int t = threadIdx.x;
    for (int i = 0; i < 16; i++) {
        int idx = i * 256 + t;
        int r = idx >> 6, c = idx & 63;
        tile[r][c] = f2bf(src[(size_t)(r0 + r) * CH + c0 + c]);
    }
    __syncthreads();
    for (int i = 0; i < 16; i++) {
        int idx = i * 256 + t;
        int oc = idx >> 6, orr = idx & 63;
        dst[(size_t)(c0 + oc) * CH + r0 + orr] = tile[orr][oc];
    }
}

// bias concat [bq|bk|bv] -> bqkv[1536]
__global__ void prep_bias(const float* __restrict__ bq, const float* __restrict__ bk,
                          const float* __restrict__ bv, float* __restrict__ bqkv) {
    int t = blockIdx.x * 256 + threadIdx.x;   // 0..1535
    bqkv[t] = t < 512 ? bq[t] : (t < 1024 ? bk[t - 512] : bv[t - 1024]);
}

// ---------------------------------------------------------------- V slice -> V^T per batch (bf16)
__global__ __launch_bounds__(256) void vt_transpose(const u16* __restrict__ in,
                                                    u16* __restrict__ out,
                                                    int R, int C, int ldIn,
                                                    long sIn, long sOut) {
    __shared__ u16 tile[64][66];
    int z = blockIdx.z;
    in  += (size_t)z * sIn;
    out += (size_t)z * sOut;
    int r0 = blockIdx.y * 64, c0 = blockIdx.x * 64;
    int t = threadIdx.x;
    for (int i = 0; i < 16; i++) {
        int idx = i * 256 + t;
        int r = idx >> 6, c = idx & 63;
        tile[r][c] = in[(size_t)(r0 + r) * ldIn + c0 + c];
    }
    __syncthreads();
    for (int i = 0; i < 16; i++) {
        int idx = i * 256 + t;
        int oc = idx >> 6, orr = idx & 63;
        out[(size_t)(c0 + oc) * R + r0 + orr] = tile[orr][oc];
    }
}

// ---------------------------------------------------------------- bf16 MFMA GEMM  (C = alpha*A*B^T (+bias) (+res))
// A: [M][K] bf16 (lda); B: [N][K] bf16 (ldb). 128x128 tile, 4 waves, 4x4 frags each.
// Chunked XCD swizzle on flattened grid (requires nb % 8 == 0).
template <bool BIAS, bool RES, bool OUTF32>
__global__ __launch_bounds__(256) void gemm_bt(
    const u16* __restrict__ A, const u16* __restrict__ B, void* __restrict__ Cout,
    const float* __restrict__ bias, const float* __restrict__ res,
    int K, int lda, int ldb, int ldc,
    long sA, long sB, long sC, float alpha) {
    __shared__ __align__(16) u16 Asm[4096];   // 8 KB
    __shared__ __align__(16) u16 Bsm[4096];

    unsigned flat = blockIdx.x + gridDim.x * (blockIdx.y + gridDim.y * blockIdx.z);
    unsigned nb = gridDim.x * gridDim.y * gridDim.z;
    unsigned lf = (flat & 7) * (nb >> 3) + (flat >> 3);
    unsigned pb = gridDim.x * gridDim.y;
    unsigned bz = lf / pb, rem = lf - bz * pb;
    unsigned by = rem / gridDim.x, bx = rem - by * gridDim.x;

    A += (size_t)bz * sA;
    B += (size_t)bz * sB;
    size_t zc = (size_t)bz * sC;

    int t = threadIdx.x;
    int wave = t >> 6, lane = t & 63;
    int wm = wave >> 1, wn = wave & 1;
    int rowA0 = by * 128;
    int colB0 = bx * 128;

    int c16log = (lane & 3) ^ ((lane >> 3) & 3);     // pre-swizzled global source
    const u16* aG[2]; const u16* bG[2]; u16* aL[2]; u16* bL[2];
#pragma unroll
    for (int j = 0; j < 2; j++) {
        int s = wave * 2 + j;
        int row = s * 16 + (lane >> 2);
        aL[j] = Asm + s * 512;
        bL[j] = Bsm + s * 512;
        aG[j] = A + (size_t)(rowA0 + row) * lda + c16log * 8;
        bG[j] = B + (size_t)(colB0 + row) * ldb + c16log * 8;
    }

    int kg = lane >> 4;
    int aoff[4], boff[4];
#pragma unroll
    for (int i = 0; i < 4; i++) {
        int ra = wm * 64 + i * 16 + (lane & 15);
        aoff[i] = ra * 32 + (kg ^ ((ra >> 1) & 3)) * 8;
        int rb = wn * 64 + i * 16 + (lane & 15);
        boff[i] = rb * 32 + (kg ^ ((rb >> 1) & 3)) * 8;
    }

    f32x4 acc[4][4] = {};
    for (int kt = 0; kt < K; kt += 32) {
        gld16(aG[0] + kt, aL[0]);
        gld16(aG[1] + kt, aL[1]);
        gld16(bG[0] + kt, bL[0]);
        gld16(bG[1] + kt, bL[1]);
        __syncthreads();
        s16x8 af[4], bfr[4];
#pragma unroll
        for (int i = 0; i < 4; i++) {
            af[i]  = *(const s16x8*)(Asm + aoff[i]);
            bfr[i] = *(const s16x8*)(Bsm + boff[i]);
        }
#pragma unroll
        for (int mi = 0; mi < 4; mi++)
#pragma unroll
            for (int nj = 0; nj < 4; nj++)
                acc[mi][nj] = __builtin_amdgcn_mfma_f32_16x16x32_bf16(
                    af[mi], bfr[nj], acc[mi][nj], 0, 0, 0);
        __syncthreads();
    }

    int r0 = rowA0 + wm * 64 + (lane >> 4) * 4;
    int c0c = colB0 + wn * 64 + (lane & 15);
#pragma unroll
    for (int mi = 0; mi < 4; mi++) {
#pragma unroll
        for (int nj = 0; nj < 4; nj++) {
            int c = c0c + nj * 16;
            float bv = BIAS ? bias[c] : 0.f;
            f32x4 v = acc[mi][nj];
#pragma unroll
            for (int j = 0; j < 4; j++) {
                int rr = r0 + mi * 16 + j;
                float val = v[j] * alpha + bv;
                if (RES) val += res[(size_t)rr * ldc + c];
                if (OUTF32) ((float*)Cout)[zc + (size_t)rr * ldc + c] = val;
                else        ((u16*)Cout)[zc + (size_t)rr * ldc + c] = f2bf(val);
            }
        }
    }
}

// ---------------------------------------------------------------- fused scores + softmax -> P (bf16)
// One block per (batch, 64-row q-tile). 512 thr = 8 waves (4 row-groups x 2 col-halves).
// Q in registers; K streamed through 64 KB LDS (BK=32, XOR-swizzled both sides).
__global__ __launch_bounds__(512, 2) void attn_fused(const u16* __restrict__ qkv,
                                                     u16* __restrict__ P) {
    __shared__ __align__(16) u16 Bsm[32768];     // 64 KB, reused for reduce + P pack

    unsigned flat = blockIdx.x;                  // 256 blocks
    unsigned lf = (flat & 7) * 32 + (flat >> 3); // 2 batches per XCD
    int b = lf >> 4, mt = lf & 15;

    int t = threadIdx.x, w = t >> 6, lane = t & 63;
    int wr = w >> 1, wn = w & 1;                 // row-group 0..3, col-half 0..1
    int l15 = lane & 15, kg = lane >> 4;

    const u16* qbase = qkv + ((size_t)b * NTOK + mt * 64) * (3 * CH);
    const u16* kbase = qkv + (size_t)b * NTOK * (3 * CH) + CH;

    // Q fragments (rows wr*16+l15, all 512 k) into registers: 16 x 8 bf16
    const u16* qrow = qbase + (size_t)(wr * 16 + l15) * (3 * CH) + kg * 8;
    s16x8 aq[16];
#pragma unroll
    for (int kt = 0; kt < 16; kt++) aq[kt] = *(const s16x8*)(qrow + kt * 32);

    // K staging: 64 segs of 16 rows; wave w stages segs w*8..w*8+7
    int c16log = (lane & 3) ^ ((lane >> 3) & 3);
    const u16* bG[8];
#pragma unroll
    for (int j = 0; j < 8; j++) {
        int row = (w * 8 + j) * 16 + (lane >> 2);
        bG[j] = kbase + (size_t)row * (3 * CH) + c16log * 8;
    }
    int rb0 = wn * 512 + l15;
    int boff = rb0 * 32 + (kg ^ ((rb0 >> 1) & 3)) * 8;   // nj stride = 512 u16

    f32x4 acc[32];
#pragma unroll
    for (int i = 0; i < 32; i++) acc[i] = f32x4{0.f, 0.f, 0.f, 0.f};

#pragma unroll
    for (int kt = 0; kt < 16; kt++) {
#pragma unroll
        for (int j = 0; j < 8; j++)
            gld16(bG[j] + kt * 32, Bsm + (w * 8 + j) * 512);
        __syncthreads();
#pragma unroll
        for (int nj = 0; nj < 32; nj++) {
            s16x8 bf = *(const s16x8*)(Bsm + boff + nj * 512);
            acc[nj] = __builtin_amdgcn_mfma_f32_16x16x32_bf16(aq[kt], bf, acc[nj], 0, 0, 0);
        }
        __syncthreads();
    }

    // ---- softmax over full 1024-row (raw scores; scale folded into exp) ----
    float* redm = (float*)Bsm;            // [64][2]
    float* reds = (float*)(Bsm + 256);    // [64][2] (256 u16 = 512 B offset)

    float mrow[4], inv[4], srow[4];
#pragma unroll
    for (int j = 0; j < 4; j++) {
        float m = acc[0][j];
#pragma unroll
        for (int nj = 1; nj < 32; nj++) m = fmaxf(m, acc[nj][j]);
        for (int off = 1; off < 16; off <<= 1) m = fmaxf(m, __shfl_xor(m, off));
        mrow[j] = m;
    }
    if (l15 == 0) {
#pragma unroll
        for (int j = 0; j < 4; j++) redm[(wr * 16 + kg * 4 + j) * 2 + wn] = mrow[j];
    }
    __syncthreads();
#pragma unroll
    for (int j = 0; j < 4; j++) {
        int row = wr * 16 + kg * 4 + j;
        mrow[j] = fmaxf(redm[row * 2], redm[row * 2 + 1]);
    }
#pragma unroll
    for (int j = 0; j < 4; j++) {
        float s = 0.f;
#pragma unroll
        for (int nj = 0; nj < 32; nj++) {
            float e = exp2f((acc[nj][j] - mrow[j]) * SEXP);
            acc[nj][j] = e;
            s += e;
        }
        for (int off = 1; off < 16; off <<= 1) s += __shfl_xor(s, off);
        srow[j] = s;
    }
    if (l15 == 0) {
#pragma unroll
        for (int j = 0; j < 4; j++) reds[(wr * 16 + kg * 4 + j) * 2 + wn] = srow[j];
    }
    __syncthreads();
#pragma unroll
    for (int j = 0; j < 4; j++) {
        int row = wr * 16 + kg * 4 + j;
        inv[j] = 1.f / (reds[row * 2] + reds[row * 2 + 1]);
    }

    // ---- pack P (bf16) through LDS, one 64x512 half at a time ----
    size_t pbase = (size_t)b * NTOK * NTOK + (size_t)mt * 64 * NTOK;
#pragma unroll
    for (int h = 0; h < 2; h++) {
        __syncthreads();     // previous users of Bsm done
        if (wn == h) {
#pragma unroll
            for (int nj = 0; nj < 32; nj++) {
                int c = nj * 16 + l15;
                int c16 = c >> 3, cw = c & 7;
#pragma unroll
                for (int j = 0; j < 4; j++) {
                    int row = wr * 16 + kg * 4 + j;
                    int pc16 = c16 ^ ((row >> 2) & 7);
                    Bsm[row * 512 + pc16 * 8 + cw] = f2bf(acc[nj][j] * inv[j]);
                }
            }
        }
        __syncthreads();
#pragma unroll
        for (int i = 0; i < 8; i++) {
            int flat16 = (i * 512 + t) * 8;
            int row = flat16 >> 9, c = flat16 & 511;
            int pc16 = (c >> 3) ^ ((row >> 2) & 7);
            uint4 vv = *(const uint4*)(Bsm + row * 512 + pc16 * 8);
            *(uint4*)(P + pbase + (size_t)row * NTOK + h * 512 + c) = vv;
        }
    }
}

// ---------------------------------------------------------------- launch
extern "C" void kernel_launch(void* const* d_in, const int* in_sizes, int n_in,
                              void* d_out, int out_size, void* d_ws, size_t ws_size,
                              hipStream_t stream) {
    const float* x     = (const float*)d_in[0];
    const float* gamma = (const float*)d_in[1];
    const float* beta  = (const float*)d_in[2];
    const float* Wq    = (const float*)d_in[3];
    const float* bq    = (const float*)d_in[4];
    const float* Wk    = (const float*)d_in[5];
    const float* bk    = (const float*)d_in[6];
    const float* Wv    = (const float*)d_in[7];
    const float* bv    = (const float*)d_in[8];
    const float* Wp    = (const float*)d_in[9];
    const float* bp    = (const float*)d_in[10];
    float* out = (float*)d_out;

    const size_t SZ  = (size_t)MTOT * CH;          // 8,388,608
    const size_t NSZ = (size_t)NTOK * CH;          // per-batch activation
    const size_t SCB = (size_t)NTOK * NTOK;        // per-batch P

    char* p = (char*)d_ws;
    float*  xn    = (float*)p;   p += SZ * 4;                     // 33.5 MB
    u16*    xnb   = (u16*)p;     p += SZ * 2;                     // 16.8 MB
    u16*    qkvb  = (u16*)p;     p += (size_t)MTOT * 3 * CH * 2;  // 50.3 MB
    u16*    vt    = (u16*)p;     p += SZ * 2;                     // 16.8 MB
    u16*    ao    = (u16*)p;     p += SZ * 2;                     // 16.8 MB
    u16*    P     = (u16*)p;     p += (size_t)BATCH * SCB * 2;    // 33.5 MB
    u16*    WTqkv = (u16*)p;     p += (size_t)3 * CH * CH * 2;    // 1.5 MB
    u16*    WTp   = (u16*)p;     p += (size_t)CH * CH * 2;        // 0.5 MB
    float*  bqkv  = (float*)p;   p += 3 * CH * 4;
    float2* stats = (float2*)p;

    dim3 blk(256);

    gn_stats<<<BATCH * NGRP, blk, 0, stream>>>(x, stats);
    gn_apply<<<2048, blk, 0, stream>>>(x, stats, gamma, beta, xn, xnb);
    weights_prep<<<dim3(8, 8, 4), blk, 0, stream>>>(Wq, Wk, Wv, Wp, WTqkv, WTp);
    prep_bias<<<6, blk, 0, stream>>>(bq, bk, bv, bqkv);

    // fused QKV: [16384x512] @ [512x1536] + bias -> qkvb bf16 (row stride 1536)
    gemm_bt<true, false, false><<<dim3(12, 128, 1), blk, 0, stream>>>(
        xnb, WTqkv, qkvb, bqkv, nullptr, CH, CH, CH, 3 * CH, 0, 0, 0, 1.f);

    // V slice -> V^T per batch
    vt_transpose<<<dim3(8, 16, BATCH), blk, 0, stream>>>(
        qkvb + 2 * CH, vt, NTOK, CH, 3 * CH, (long)NTOK * 3 * CH, (long)NSZ);

    // fused scores+softmax -> P bf16
    attn_fused<<<256, 512, 0, stream>>>(qkvb, P);

    // out_attn = P @ V (batched): A=P [1024x1024], B=vt [512][1024] -> ao bf16
    gemm_bt<false, false, false><<<dim3(4, 8, BATCH), blk, 0, stream>>>(
        P, vt, ao, nullptr, nullptr, NTOK, NTOK, NTOK, CH,
        (long)SCB, (long)NSZ, (long)NSZ, 1.f);

    // proj + bias + residual(xn f32) -> out f32
    gemm_bt<true, true, true><<<dim3(4, 128, 1), blk, 0, stream>>>(
        ao, WTp, out, bp, xn, CH, CH, CH, CH, 0, 0, 0, 1.f);
}

// Round 5
// 262.169 us; speedup vs baseline: 1.1890x; 1.0299x over previous
//
#include <hip/hip_runtime.h>
#include <math.h>

// Problem constants (B,H,W,C = 16,32,32,512; 32 groups)
#define BATCH 16
#define NTOK  1024
#define CH    512
#define NGRP  32
#define GSZ   16
#define EPSV  1e-3f
#define MTOT  (BATCH*NTOK)          // 16384
#define SCALE 0.04419417382415922f  // 512^-0.5
#define SEXP  (SCALE*1.4426950408889634f)   // scale*log2(e), for exp2

typedef unsigned short u16;
typedef __attribute__((ext_vector_type(4))) float f32x4;
typedef __attribute__((ext_vector_type(8))) short s16x8;

__device__ __forceinline__ u16 f2bf(float f) {           // RNE float->bf16
    union { float f; unsigned u; } x{f};
    unsigned r = x.u + 0x7fff + ((x.u >> 16) & 1);
    return (u16)(r >> 16);
}

__device__ __forceinline__ void gld16(const u16* g, u16* l) {
    __builtin_amdgcn_global_load_lds(
        (const __attribute__((address_space(1))) void*)g,
        (__attribute__((address_space(3))) void*)l, 16, 0, 0);
}

// ---------------------------------------------------------------- group-norm stats
__global__ __launch_bounds__(256) void gn_stats(const float* __restrict__ x,
                                                float2* __restrict__ stats) {
    int bg = blockIdx.x;             // batch*32 + group
    int b = bg >> 5, g = bg & 31;
    const float* base = x + (size_t)b * NTOK * CH + g * GSZ;
    float s = 0.f, ss = 0.f;
    for (int i = threadIdx.x; i < 4096; i += 256) {
        int p = i >> 2, c4 = i & 3;
        float4 v = *(const float4*)(base + (size_t)p * CH + c4 * 4);
        s  += v.x + v.y + v.z + v.w;
        ss += v.x * v.x + v.y * v.y + v.z * v.z + v.w * v.w;
    }
    for (int off = 32; off; off >>= 1) {
        s  += __shfl_down(s, off);
        ss += __shfl_down(ss, off);
    }
    __shared__ float2 part[4];
    if ((threadIdx.x & 63) == 0) part[threadIdx.x >> 6] = make_float2(s, ss);
    __syncthreads();
    if (threadIdx.x == 0) {
        float S = 0.f, SS = 0.f;
        for (int i = 0; i < 4; i++) { S += part[i].x; SS += part[i].y; }
        float mean = S * (1.f / 16384.f);
        float var  = SS * (1.f / 16384.f) - mean * mean;
        stats[bg] = make_float2(mean, rsqrtf(var + EPSV));
    }
}

// ---------------------------------------------------------------- apply norm -> xn(f32) + xnb(bf16)
__global__ __launch_bounds__(256) void gn_apply(const float* __restrict__ x,
                                                const float2* __restrict__ stats,
                                                const float* __restrict__ gamma,
                                                const float* __restrict__ beta,
                                                float* __restrict__ xn,
                                                u16* __restrict__ xnb) {
    size_t total = (size_t)MTOT * CH / 4;
    for (size_t i4 = (size_t)blockIdx.x * 256 + threadIdx.x; i4 < total;
         i4 += (size_t)gridDim.x * 256) {
        size_t flat = i4 * 4;
        int c = (int)(flat & (CH - 1));
        int b = (int)(flat >> 19);
        int g = c >> 4;
        float2 st = stats[(b << 5) + g];
        float4 xv = *(const float4*)(x + flat);
        float4 gv = *(const float4*)(gamma + c);
        float4 bv = *(const float4*)(beta + c);
        float4 o;
        o.x = (xv.x - st.x) * st.y * gv.x + bv.x;
        o.y = (xv.y - st.x) * st.y * gv.y + bv.y;
        o.z = (xv.z - st.x) * st.y * gv.z + bv.z;
        o.w = (xv.w - st.x) * st.y * gv.w + bv.w;
        *(float4*)(xn + flat) = o;
        uint2 h;
        h.x = (unsigned)f2bf(o.x) | ((unsigned)f2bf(o.y) << 16);
        h.y = (unsigned)f2bf(o.z) | ((unsigned)f2bf(o.w) << 16);
        *(uint2*)(xnb + flat) = h;
    }
}

// ---------------------------------------------------------------- weights: transpose f32->bf16, all 4 in one dispatch
__global__ __launch_bounds__(256) void weights_prep(
    const float* __restrict__ Wq, const float* __restrict__ Wk,
    const float* __restrict__ Wv, const float* __restrict__ Wp,
    u16* __restrict__ WTqkv, u16* __restrict__ WTp) {
    int z = blockIdx.z;
    const float* src = z == 0 ? Wq : z == 1 ? Wk : z == 2 ? Wv : Wp;
    u16* dst = z < 3 ? WTqkv + (size_t)z * CH * CH : WTp;
    __shared__ u16 tile[64][66];
    int r0 = blockIdx.y * 64, c0 = blockIdx.x * 64;
    int t = threadIdx.x;
    for (int i = 0; i < 16; i++) {
        int idx = i * 256 + t;
        int r = idx >> 6, c = idx & 63;
        tile[r][c] = f2bf(src[(size_t)(r0 + r) * CH + c0 + c]);
    }
    __syncthreads();
    for (int i = 0; i < 16; i++) {
        int idx = i * 256 + t;
        int oc = idx >> 6, orr = idx & 63;
        dst[(size_t)(c0 + oc) * CH + r0 + orr] = tile[orr][oc];
    }
}

// bias concat [bq|bk|bv] -> bqkv[1536]
__global__ void prep_bias(const float* __restrict__ bq, const float* __restrict__ bk,
                          const float* __restrict__ bv, float* __restrict__ bqkv) {
    int t = blockIdx.x * 256 + threadIdx.x;   // 0..1535
    bqkv[t] = t < 512 ? bq[t] : (t < 1024 ? bk[t - 512] : bv[t - 1024]);
}

// ---------------------------------------------------------------- V slice -> V^T per batch (bf16)
__global__ __launch_bounds__(256) void vt_transpose(const u16* __restrict__ in,
                                                    u16* __restrict__ out,
                                                    int R, int C, int ldIn,
                                                    long sIn, long sOut) {
    __shared__ u16 tile[64][66];
    int z = blockIdx.z;
    in  += (size_t)z * sIn;
    out += (size_t)z * sOut;
    int r0 = blockIdx.y * 64, c0 = blockIdx.x * 64;
    int t = threadIdx.x;
    for (int i = 0; i < 16; i++) {
        int idx = i * 256 + t;
        int r = idx >> 6, c = idx & 63;
        tile[r][c] = in[(size_t)(r0 + r) * ldIn + c0 + c];
    }
    __syncthreads();
    for (int i = 0; i < 16; i++) {
        int idx = i * 256 + t;
        int oc = idx >> 6, orr = idx & 63;
        out[(size_t)(c0 + oc) * R + r0 + orr] = tile[orr][oc];
    }
}

// ---------------------------------------------------------------- bf16 MFMA GEMM  (C = alpha*A*B^T (+bias) (+res))
// A: [M][K] bf16 (lda); B: [N][K] bf16 (ldb). 128x128 tile, 4 waves, 4x4 frags each.
// Double-buffered LDS (2x16KB), 2-phase: stage kt+1, MFMA kt, ONE barrier per K-step.
// Chunked XCD swizzle on flattened grid (requires nb % 8 == 0).
template <bool BIAS, bool RES, bool OUTF32>
__global__ __launch_bounds__(256) void gemm_bt(
    const u16* __restrict__ A, const u16* __restrict__ B, void* __restrict__ Cout,
    const float* __restrict__ bias, const float* __restrict__ res,
    int K, int lda, int ldb, int ldc,
    long sA, long sB, long sC, float alpha) {
    __shared__ __align__(16) u16 Asm[8192];   // 2 x 8 KB
    __shared__ __align__(16) u16 Bsm[8192];

    unsigned flat = blockIdx.x + gridDim.x * (blockIdx.y + gridDim.y * blockIdx.z);
    unsigned nb = gridDim.x * gridDim.y * gridDim.z;
    unsigned lf = (flat & 7) * (nb >> 3) + (flat >> 3);
    unsigned pb = gridDim.x * gridDim.y;
    unsigned bz = lf / pb, rem = lf - bz * pb;
    unsigned by = rem / gridDim.x, bx = rem - by * gridDim.x;

    A += (size_t)bz * sA;
    B += (size_t)bz * sB;
    size_t zc = (size_t)bz * sC;

    int t = threadIdx.x;
    int wave = t >> 6, lane = t & 63;
    int wm = wave >> 1, wn = wave & 1;
    int rowA0 = by * 128;
    int colB0 = bx * 128;

    int c16log = (lane & 3) ^ ((lane >> 3) & 3);     // pre-swizzled global source
    const u16* aG[2]; const u16* bG[2]; u16* aL[2]; u16* bL[2];
#pragma unroll
    for (int j = 0; j < 2; j++) {
        int s = wave * 2 + j;
        int row = s * 16 + (lane >> 2);
        aL[j] = Asm + s * 512;
        bL[j] = Bsm + s * 512;
        aG[j] = A + (size_t)(rowA0 + row) * lda + c16log * 8;
        bG[j] = B + (size_t)(colB0 + row) * ldb + c16log * 8;
    }

    int kg = lane >> 4;
    int aoff[4], boff[4];
#pragma unroll
    for (int i = 0; i < 4; i++) {
        int ra = wm * 64 + i * 16 + (lane & 15);
        aoff[i] = ra * 32 + (kg ^ ((ra >> 1) & 3)) * 8;
        int rb = wn * 64 + i * 16 + (lane & 15);
        boff[i] = rb * 32 + (kg ^ ((rb >> 1) & 3)) * 8;
    }

#define STG_G(buf, ktE)                          \
    {                                            \
        gld16(aG[0] + (ktE), aL[0] + (buf) * 4096); \
        gld16(aG[1] + (ktE), aL[1] + (buf) * 4096); \
        gld16(bG[0] + (ktE), bL[0] + (buf) * 4096); \
        gld16(bG[1] + (ktE), bL[1] + (buf) * 4096); \
    }

    f32x4 acc[4][4] = {};
    int nk = K >> 5;
    STG_G(0, 0);
    __syncthreads();
    for (int kt = 0; kt < nk; kt++) {
        if (kt + 1 < nk) STG_G((kt + 1) & 1, (kt + 1) * 32);
        const u16* as = Asm + (kt & 1) * 4096;
        const u16* bs = Bsm + (kt & 1) * 4096;
        s16x8 af[4], bfr[4];
#pragma unroll
        for (int i = 0; i < 4; i++) {
            af[i]  = *(const s16x8*)(as + aoff[i]);
            bfr[i] = *(const s16x8*)(bs + boff[i]);
        }
#pragma unroll
        for (int mi = 0; mi < 4; mi++)
#pragma unroll
            for (int nj = 0; nj < 4; nj++)
                acc[mi][nj] = __builtin_amdgcn_mfma_f32_16x16x32_bf16(
                    af[mi], bfr[nj], acc[mi][nj], 0, 0, 0);
        __syncthreads();   // reads of buf kt done; staged tile kt+1 drained
    }
#undef STG_G

    int r0 = rowA0 + wm * 64 + (lane >> 4) * 4;
    int c0c = colB0 + wn * 64 + (lane & 15);
#pragma unroll
    for (int mi = 0; mi < 4; mi++) {
#pragma unroll
        for (int nj = 0; nj < 4; nj++) {
            int c = c0c + nj * 16;
            float bv = BIAS ? bias[c] : 0.f;
            f32x4 v = acc[mi][nj];
#pragma unroll
            for (int j = 0; j < 4; j++) {
                int rr = r0 + mi * 16 + j;
                float val = v[j] * alpha + bv;
                if (RES) val += res[(size_t)rr * ldc + c];
                if (OUTF32) ((float*)Cout)[zc + (size_t)rr * ldc + c] = val;
                else        ((u16*)Cout)[zc + (size_t)rr * ldc + c] = f2bf(val);
            }
        }
    }
}

// ---------------------------------------------------------------- fused scores + softmax -> P (bf16)
// One block per (batch, 64-row q-tile). 512 thr = 8 waves (4 row-groups x 2 col-halves).
// Q in registers; K double-buffered through 2x64KB LDS (BK=32, XOR-swizzled both sides).
// 2-phase schedule: stage K-tile kt+1, MFMA on kt, ONE barrier per kt (T3 minimum recipe).
__global__ __launch_bounds__(512, 2) void attn_fused(const u16* __restrict__ qkv,
                                                     u16* __restrict__ P) {
    __shared__ __align__(16) u16 Bsm[65536];     // 2 x 64 KB K tiles (reused for reduce/pack)

    unsigned flat = blockIdx.x;                  // 256 blocks
    unsigned lf = (flat & 7) * 32 + (flat >> 3); // 2 batches per XCD
    int b = lf >> 4, mt = lf & 15;

    int t = threadIdx.x, w = t >> 6, lane = t & 63;
    int wr = w >> 1, wn = w & 1;                 // row-group 0..3, col-half 0..1
    int l15 = lane & 15, kg = lane >> 4;

    const u16* qbase = qkv + ((size_t)b * NTOK + mt * 64) * (3 * CH);
    const u16* kbase = qkv + (size_t)b * NTOK * (3 * CH) + CH;

    // Q fragments (rows wr*16+l15, all 512 k) into registers: 16 x 8 bf16
    const u16* qrow = qbase + (size_t)(wr * 16 + l15) * (3 * CH) + kg * 8;
    s16x8 aq[16];
#pragma unroll
    for (int kt = 0; kt < 16; kt++) aq[kt] = *(const s16x8*)(qrow + kt * 32);

    // K staging: 64 segs of 16 rows; wave w stages segs w*8..w*8+7
    int c16log = (lane & 3) ^ ((lane >> 3) & 3);
    const u16* bG[8];
#pragma unroll
    for (int j = 0; j < 8; j++) {
        int row = (w * 8 + j) * 16 + (lane >> 2);
        bG[j] = kbase + (size_t)row * (3 * CH) + c16log * 8;
    }
    int rb0 = wn * 512 + l15;
    int boff = rb0 * 32 + (kg ^ ((rb0 >> 1) & 3)) * 8;   // nj stride = 512 u16

    f32x4 acc[32];
#pragma unroll
    for (int i = 0; i < 32; i++) acc[i] = f32x4{0.f, 0.f, 0.f, 0.f};

#define STG(buf, kt)                                                        \
    {                                                                       \
        _Pragma("unroll")                                                   \
        for (int j = 0; j < 8; j++)                                         \
            gld16(bG[j] + (kt) * 32, Bsm + (buf) * 32768 + (w * 8 + j) * 512); \
    }

    STG(0, 0);
    __syncthreads();
#pragma unroll
    for (int kt = 0; kt < 16; kt++) {
        if (kt < 15) STG((kt + 1) & 1, kt + 1);          // prefetch next tile
        const u16* bb = Bsm + (kt & 1) * 32768;
#pragma unroll
        for (int nj = 0; nj < 32; nj++) {
            s16x8 bf = *(const s16x8*)(bb + boff + nj * 512);
            acc[nj] = __builtin_amdgcn_mfma_f32_16x16x32_bf16(aq[kt], bf, acc[nj], 0, 0, 0);
        }
        __syncthreads();   // drains this kt's ds_reads + next tile's vmcnt together
    }
#undef STG

    // ---- softmax over full 1024-row (raw scores; scale folded into exp) ----
    float* redm = (float*)Bsm;            // [64][2]
    float* reds = (float*)(Bsm + 256);    // [64][2] (256 u16 = 512 B offset)

    float mrow[4], inv[4], srow[4];
#pragma unroll
    for (int j = 0; j < 4; j++) {
        float m = acc[0][j];
#pragma unroll
        for (int nj = 1; nj < 32; nj++) m = fmaxf(m, acc[nj][j]);
        for (int off = 1; off < 16; off <<= 1) m = fmaxf(m, __shfl_xor(m, off));
        mrow[j] = m;
    }
    if (l15 == 0) {
#pragma unroll
        for (int j = 0; j < 4; j++) redm[(wr * 16 + kg * 4 + j) * 2 + wn] = mrow[j];
    }
    __syncthreads();
#pragma unroll
    for (int j = 0; j < 4; j++) {
        int row = wr * 16 + kg * 4 + j;
        mrow[j] = fmaxf(redm[row * 2], redm[row * 2 + 1]);
    }
#pragma unroll
    for (int j = 0; j < 4; j++) {
        float s = 0.f;
#pragma unroll
        for (int nj = 0; nj < 32; nj++) {
            float e = exp2f((acc[nj][j] - mrow[j]) * SEXP);
            acc[nj][j] = e;
            s += e;
        }
        for (int off = 1; off < 16; off <<= 1) s += __shfl_xor(s, off);
        srow[j] = s;
    }
    if (l15 == 0) {
#pragma unroll
        for (int j = 0; j < 4; j++) reds[(wr * 16 + kg * 4 + j) * 2 + wn] = srow[j];
    }
    __syncthreads();
#pragma unroll
    for (int j = 0; j < 4; j++) {
        int row = wr * 16 + kg * 4 + j;
        inv[j] = 1.f / (reds[row * 2] + reds[row * 2 + 1]);
    }

    // ---- pack P (bf16) through LDS, one 64x512 half at a time ----
    size_t pbase = (size_t)b * NTOK * NTOK + (size_t)mt * 64 * NTOK;
#pragma unroll
    for (int h = 0; h < 2; h++) {
        __syncthreads();     // previous users of Bsm done
        if (wn == h) {
#pragma unroll
            for (int nj = 0; nj < 32; nj++) {
                int c = nj * 16 + l15;
                int c16 = c >> 3, cw = c & 7;
#pragma unroll
                for (int j = 0; j < 4; j++) {
                    int row = wr * 16 + kg * 4 + j;
                    int pc16 = c16 ^ ((row >> 2) & 7);
                    Bsm[row * 512 + pc16 * 8 + cw] = f2bf(acc[nj][j] * inv[j]);
                }
            }
        }
        __syncthreads();
#pragma unroll
        for (int i = 0; i < 8; i++) {
            int flat16 = (i * 512 + t) * 8;
            int row = flat16 >> 9, c = flat16 & 511;
            int pc16 = (c >> 3) ^ ((row >> 2) & 7);
            uint4 vv = *(const uint4*)(Bsm + row * 512 + pc16 * 8);
            *(uint4*)(P + pbase + (size_t)row * NTOK + h * 512 + c) = vv;
        }
    }
}

// ---------------------------------------------------------------- launch
extern "C" void kernel_launch(void* const* d_in, const int* in_sizes, int n_in,
                              void* d_out, int out_size, void* d_ws, size_t ws_size,
                              hipStream_t stream) {
    const float* x     = (const float*)d_in[0];
    const float* gamma = (const float*)d_in[1];
    const float* beta  = (const float*)d_in[2];
    const float* Wq    = (const float*)d_in[3];
    const float* bq    = (const float*)d_in[4];
    const float* Wk    = (const float*)d_in[5];
    const float* bk    = (const float*)d_in[6];
    const float* Wv    = (const float*)d_in[7];
    const float* bv    = (const float*)d_in[8];
    const float* Wp    = (const float*)d_in[9];
    const float* bp    = (const float*)d_in[10];
    float* out = (float*)d_out;

    const size_t SZ  = (size_t)MTOT * CH;          // 8,388,608
    const size_t NSZ = (size_t)NTOK * CH;          // per-batch activation
    const size_t SCB = (size_t)NTOK * NTOK;        // per-batch P

    char* p = (char*)d_ws;
    float*  xn    = (float*)p;   p += SZ * 4;                     // 33.5 MB
    u16*    xnb   = (u16*)p;     p += SZ * 2;                     // 16.8 MB
    u16*    qkvb  = (u16*)p;     p += (size_t)MTOT * 3 * CH * 2;  // 50.3 MB
    u16*    vt    = (u16*)p;     p += SZ * 2;                     // 16.8 MB
    u16*    ao    = (u16*)p;     p += SZ * 2;                     // 16.8 MB
    u16*    P     = (u16*)p;     p += (size_t)BATCH * SCB * 2;    // 33.5 MB
    u16*    WTqkv = (u16*)p;     p += (size_t)3 * CH * CH * 2;    // 1.5 MB
    u16*    WTp   = (u16*)p;     p += (size_t)CH * CH * 2;        // 0.5 MB
    float*  bqkv  = (float*)p;   p += 3 * CH * 4;
    float2* stats = (float2*)p;

    dim3 blk(256);

    gn_stats<<<BATCH * NGRP, blk, 0, stream>>>(x, stats);
    gn_apply<<<2048, blk, 0, stream>>>(x, stats, gamma, beta, xn, xnb);
    weights_prep<<<dim3(8, 8, 4), blk, 0, stream>>>(Wq, Wk, Wv, Wp, WTqkv, WTp);
    prep_bias<<<6, blk, 0, stream>>>(bq, bk, bv, bqkv);

    // fused QKV: [16384x512] @ [512x1536] + bias -> qkvb bf16 (row stride 1536)
    gemm_bt<true, false, false><<<dim3(12, 128, 1), blk, 0, stream>>>(
        xnb, WTqkv, qkvb, bqkv, nullptr, CH, CH, CH, 3 * CH, 0, 0, 0, 1.f);

    // V slice -> V^T per batch
    vt_transpose<<<dim3(8, 16, BATCH), blk, 0, stream>>>(
        qkvb + 2 * CH, vt, NTOK, CH, 3 * CH, (long)NTOK * 3 * CH, (long)NSZ);

    // fused scores+softmax -> P bf16
    attn_fused<<<256, 512, 0, stream>>>(qkvb, P);

    // out_attn = P @ V (batched): A=P [1024x1024], B=vt [512][1024] -> ao bf16
    gemm_bt<false, false, false><<<dim3(4, 8, BATCH), blk, 0, stream>>>(
        P, vt, ao, nullptr, nullptr, NTOK, NTOK, NTOK, CH,
        (long)SCB, (long)NSZ, (long)NSZ, 1.f);

    // proj + bias + residual(xn f32) -> out f32
    gemm_bt<true, true, true><<<dim3(4, 128, 1), blk, 0, stream>>>(
        ao, WTp, out, bp, xn, CH, CH, CH, CH, 0, 0, 0, 1.f);
}